// Round 2
// baseline (344.373 us; speedup 1.0000x reference)
//
#include <hip/hip_runtime.h>

#define BB 2
#define TT 1024
#define DD 512
#define HH 8
#define FF 16
#define HDIM 64
#define BT (BB*TT)   // 2048
#define NPAIR 36     // 8*9/2 causal chunk pairs (128-row chunks)

// ---------------------------------------------------------------------------
// Kernel 1: fused QKV projection.  C = X @ [Wq;Wk;Wv]^T  (2048 x 768, K=512)
// ---------------------------------------------------------------------------
__global__ __launch_bounds__(256) void qkv_gemm_kernel(
    const float* __restrict__ X, const float* __restrict__ Wq,
    const float* __restrict__ Wk, const float* __restrict__ Wv,
    float* __restrict__ Qo, float* __restrict__ Ko, float* __restrict__ Vo)
{
    __shared__ float As[16][64];
    __shared__ float Bs[16][64];
    const int m0 = blockIdx.x * 64;
    const int n0 = blockIdx.y * 64;
    const int tid = threadIdx.x;
    const int tx = tid & 15, ty = tid >> 4;
    const int lrow = tid >> 2, lseg = tid & 3;

    const float* Wb; int nb;
    if (n0 < 128)      { Wb = Wq; nb = n0; }
    else if (n0 < 256) { Wb = Wk; nb = n0 - 128; }
    else               { Wb = Wv; nb = n0 - 256; }

    float acc[4][4] = {};
    for (int k0 = 0; k0 < DD; k0 += 16) {
        float4 a  = *(const float4*)(X  + (size_t)(m0 + lrow) * DD + k0 + lseg * 4);
        float4 bv = *(const float4*)(Wb + (size_t)(nb + lrow) * DD + k0 + lseg * 4);
        __syncthreads();
        As[lseg*4+0][lrow] = a.x;  As[lseg*4+1][lrow] = a.y;
        As[lseg*4+2][lrow] = a.z;  As[lseg*4+3][lrow] = a.w;
        Bs[lseg*4+0][lrow] = bv.x; Bs[lseg*4+1][lrow] = bv.y;
        Bs[lseg*4+2][lrow] = bv.z; Bs[lseg*4+3][lrow] = bv.w;
        __syncthreads();
        #pragma unroll
        for (int k = 0; k < 16; ++k) {
            float4 av = *(const float4*)&As[k][ty*4];
            float4 bw = *(const float4*)&Bs[k][tx*4];
            const float* ap = (const float*)&av;
            const float* bp = (const float*)&bw;
            #pragma unroll
            for (int i = 0; i < 4; ++i)
                #pragma unroll
                for (int j = 0; j < 4; ++j)
                    acc[i][j] = fmaf(ap[i], bp[j], acc[i][j]);
        }
    }

    #pragma unroll
    for (int i = 0; i < 4; ++i) {
        const int rg = m0 + ty*4 + i;
        const int bb = rg >> 10, t = rg & 1023;
        #pragma unroll
        for (int j = 0; j < 4; ++j) {
            const int cg = n0 + tx*4 + j;
            const float val = acc[i][j];
            if (cg < 128) {
                const int hh = cg >> 4, f = cg & 15;
                Qo[((size_t)(bb*HH + hh)*TT + t)*FF + f] = val;
            } else if (cg < 256) {
                const int c = cg - 128; const int hh = c >> 4, f = c & 15;
                Ko[((size_t)(bb*HH + hh)*TT + t)*FF + f] = val;
            } else {
                const int c = cg - 256; const int hh = c >> 6, dd = c & 63;
                Vo[((size_t)(bb*HH + hh)*TT + t)*HDIM + dd] = val;
            }
        }
    }
}

// ---------------------------------------------------------------------------
// Kernel 2: split-K causal Taylor attention.
// One block = one causal (q-chunk, k-chunk) 128x128 tile pair; 36 pairs x
// 16 (b,h) = 576 equal-work blocks. Partial num/den accumulated into zeroed
// workspace with fp32 atomics.
// Thread layout: ty(0..63) owns q-rows 2ty,2ty+1; tx(0..3) owns 16 v-cols.
// phi(q).phi(k) == 1 + s + s^2/2,  s = (q.k)/4.
// ---------------------------------------------------------------------------
__global__ __launch_bounds__(256) void attn_chunk_kernel(
    const float* __restrict__ Q, const float* __restrict__ K,
    const float* __restrict__ V, float* __restrict__ NUM,
    float* __restrict__ DEN)
{
    const int p  = blockIdx.x;   // 0..35
    const int bh = blockIdx.y;   // 0..15

    int qt = (int)((sqrtf(8.0f * p + 1.0f) - 1.0f) * 0.5f);
    while ((qt + 1) * (qt + 2) / 2 <= p) ++qt;
    while (qt * (qt + 1) / 2 > p) --qt;
    const int kc = p - qt * (qt + 1) / 2;

    const int tid = threadIdx.x;
    const int tx = tid & 3;      // col group: cols tx*16 .. tx*16+15
    const int ty = tid >> 2;     // 0..63: q-rows 2ty, 2ty+1

    __shared__ float Ks[128][16];
    __shared__ float Vs[128][64];

    // stage K/V chunk (128 rows)
    {
        const float4* Kb4 = (const float4*)(K + ((size_t)bh*TT + kc*128) * FF);
        float4* Ks4 = (float4*)&Ks[0][0];
        for (int u = tid; u < 512; u += 256) Ks4[u] = Kb4[u];
        const float4* Vb4 = (const float4*)(V + ((size_t)bh*TT + kc*128) * HDIM);
        float4* Vs4 = (float4*)&Vs[0][0];
        for (int u = tid; u < 2048; u += 256) Vs4[u] = Vb4[u];
    }

    // this thread's two q-rows into registers
    float q0[16], q1[16];
    const float* Qb = Q + ((size_t)bh * TT + qt * 128) * FF;
    #pragma unroll
    for (int s = 0; s < 4; ++s) {
        float4 a = *(const float4*)(Qb + (ty*2 + 0)*FF + s*4);
        q0[s*4+0]=a.x; q0[s*4+1]=a.y; q0[s*4+2]=a.z; q0[s*4+3]=a.w;
        float4 b = *(const float4*)(Qb + (ty*2 + 1)*FF + s*4);
        q1[s*4+0]=b.x; q1[s*4+1]=b.y; q1[s*4+2]=b.z; q1[s*4+3]=b.w;
    }
    __syncthreads();

    float num0[16] = {}, num1[16] = {};
    float den0 = 0.f, den1 = 0.f;
    const bool diag = (kc == qt);
    const int r0 = ty * 2, r1 = ty * 2 + 1;

    #pragma unroll 2
    for (int kk = 0; kk < 128; ++kk) {
        float kv[16];
        #pragma unroll
        for (int s = 0; s < 4; ++s) {
            float4 t4 = *(const float4*)&Ks[kk][s*4];
            kv[s*4+0]=t4.x; kv[s*4+1]=t4.y; kv[s*4+2]=t4.z; kv[s*4+3]=t4.w;
        }
        float vv[16];
        #pragma unroll
        for (int s = 0; s < 4; ++s) {
            float4 t4 = *(const float4*)&Vs[kk][tx*16 + s*4];
            vv[s*4+0]=t4.x; vv[s*4+1]=t4.y; vv[s*4+2]=t4.z; vv[s*4+3]=t4.w;
        }
        float s0 = 0.f, s1 = 0.f;
        #pragma unroll
        for (int m = 0; m < 16; ++m) {
            s0 = fmaf(q0[m], kv[m], s0);
            s1 = fmaf(q1[m], kv[m], s1);
        }
        s0 *= 0.25f; s1 *= 0.25f;
        float p0 = fmaf(s0, fmaf(s0, 0.5f, 1.0f), 1.0f);
        float p1 = fmaf(s1, fmaf(s1, 0.5f, 1.0f), 1.0f);
        if (diag) {
            p0 = (kk <= r0) ? p0 : 0.f;
            p1 = (kk <= r1) ? p1 : 0.f;
        }
        den0 += p0; den1 += p1;
        #pragma unroll
        for (int j = 0; j < 16; ++j) {
            num0[j] = fmaf(p0, vv[j], num0[j]);
            num1[j] = fmaf(p1, vv[j], num1[j]);
        }
    }

    // atomic epilogue into (bh, t, hd) partial buffers
    float* nb = NUM + ((size_t)bh * TT + qt * 128) * HDIM;
    #pragma unroll
    for (int j = 0; j < 16; ++j) {
        atomicAdd(&nb[(size_t)r0 * HDIM + tx*16 + j], num0[j]);
        atomicAdd(&nb[(size_t)r1 * HDIM + tx*16 + j], num1[j]);
    }
    if (tx == 0) {
        atomicAdd(&DEN[(size_t)bh * TT + qt*128 + r0], den0);
        atomicAdd(&DEN[(size_t)bh * TT + qt*128 + r1], den1);
    }
}

// ---------------------------------------------------------------------------
// Kernel 2b: normalize and relayout to (b, t, h*hd)
// ---------------------------------------------------------------------------
__global__ __launch_bounds__(256) void normalize_kernel(
    const float* __restrict__ NUM, const float* __restrict__ DEN,
    float* __restrict__ Y)
{
    const int idx = blockIdx.x * 256 + threadIdx.x;  // 0 .. 16*1024*64
    const int c  = idx & 63;
    const int t  = (idx >> 6) & 1023;
    const int bh = idx >> 16;
    const int b = bh >> 3, h = bh & 7;
    const float d = DEN[(size_t)bh * TT + t] + 1e-12f;
    Y[((size_t)(b * TT + t)) * DD + h * HDIM + c] = NUM[idx] / d;
}

// ---------------------------------------------------------------------------
// Kernel 3: output projection.  Out = Y @ Wo^T  (2048 x 512, K=512)
// ---------------------------------------------------------------------------
__global__ __launch_bounds__(256) void out_gemm_kernel(
    const float* __restrict__ Yin, const float* __restrict__ Wo,
    float* __restrict__ Out)
{
    __shared__ float As[16][64];
    __shared__ float Bs[16][64];
    const int m0 = blockIdx.x * 64;
    const int n0 = blockIdx.y * 64;
    const int tid = threadIdx.x;
    const int tx = tid & 15, ty = tid >> 4;
    const int lrow = tid >> 2, lseg = tid & 3;

    float acc[4][4] = {};
    for (int k0 = 0; k0 < DD; k0 += 16) {
        float4 a  = *(const float4*)(Yin + (size_t)(m0 + lrow) * DD + k0 + lseg * 4);
        float4 bv = *(const float4*)(Wo  + (size_t)(n0 + lrow) * DD + k0 + lseg * 4);
        __syncthreads();
        As[lseg*4+0][lrow] = a.x;  As[lseg*4+1][lrow] = a.y;
        As[lseg*4+2][lrow] = a.z;  As[lseg*4+3][lrow] = a.w;
        Bs[lseg*4+0][lrow] = bv.x; Bs[lseg*4+1][lrow] = bv.y;
        Bs[lseg*4+2][lrow] = bv.z; Bs[lseg*4+3][lrow] = bv.w;
        __syncthreads();
        #pragma unroll
        for (int k = 0; k < 16; ++k) {
            float4 av = *(const float4*)&As[k][ty*4];
            float4 bw = *(const float4*)&Bs[k][tx*4];
            const float* ap = (const float*)&av;
            const float* bp = (const float*)&bw;
            #pragma unroll
            for (int i = 0; i < 4; ++i)
                #pragma unroll
                for (int j = 0; j < 4; ++j)
                    acc[i][j] = fmaf(ap[i], bp[j], acc[i][j]);
        }
    }

    #pragma unroll
    for (int i = 0; i < 4; ++i) {
        const int rg = m0 + ty*4 + i;
        #pragma unroll
        for (int j = 0; j < 4; ++j) {
            const int cg = n0 + tx*4 + j;
            Out[(size_t)rg * DD + cg] = acc[i][j];
        }
    }
}

// ---------------------------------------------------------------------------
extern "C" void kernel_launch(void* const* d_in, const int* in_sizes, int n_in,
                              void* d_out, int out_size, void* d_ws, size_t ws_size,
                              hipStream_t stream) {
    const float* X  = (const float*)d_in[0];   // (2,1024,512)
    const float* Wq = (const float*)d_in[1];   // (128,512)
    const float* Wk = (const float*)d_in[2];   // (128,512)
    const float* Wv = (const float*)d_in[3];   // (512,512)
    const float* Wo = (const float*)d_in[4];   // (512,512)
    float* out = (float*)d_out;                // (2,1024,512)

    float* ws = (float*)d_ws;
    float* Qw  = ws;                         // 2*8*1024*16  = 262144
    float* Kw  = Qw + (size_t)BB*HH*TT*FF;   // 262144
    float* Vw  = Kw + (size_t)BB*HH*TT*FF;   // 1048576
    float* Yw  = Vw + (size_t)BB*HH*TT*HDIM; // 1048576
    float* NUMw = Yw + (size_t)BT*DD;        // 1048576
    float* DENw = NUMw + (size_t)BB*HH*TT*HDIM; // 16384

    dim3 g1(BT/64, 768/64);   // 32 x 12
    qkv_gemm_kernel<<<g1, 256, 0, stream>>>(X, Wq, Wk, Wv, Qw, Kw, Vw);

    // zero num/den partial accumulators (contiguous region)
    hipMemsetAsync(NUMw, 0, ((size_t)BB*HH*TT*HDIM + (size_t)BB*HH*TT) * sizeof(float), stream);

    dim3 g2(NPAIR, BB*HH);    // 36 x 16 = 576 equal-work blocks
    attn_chunk_kernel<<<g2, 256, 0, stream>>>(Qw, Kw, Vw, NUMw, DENw);

    dim3 g2b((BB*HH*TT*HDIM)/256);  // 4096
    normalize_kernel<<<g2b, 256, 0, stream>>>(NUMw, DENw, Yw);

    dim3 g3(BT/64, DD/64);    // 32 x 8
    out_gemm_kernel<<<g3, 256, 0, stream>>>(Yw, Wo, out);
}

// Round 3
// 121.627 us; speedup vs baseline: 2.8314x; 2.8314x over previous
//
#include <hip/hip_runtime.h>

#define BB 2
#define TT 1024
#define DD 512
#define HH 8
#define FF 16
#define HDIM 64
#define BT (BB*TT)   // 2048
#define NPAIR 36     // 8*9/2 causal chunk pairs (128-row chunks)
#define NKC 8        // k-chunks (slots)

// ---------------------------------------------------------------------------
// Kernel 1: fused QKV projection.  C = X @ [Wq;Wk;Wv]^T  (2048 x 768, K=512)
// ---------------------------------------------------------------------------
__global__ __launch_bounds__(256) void qkv_gemm_kernel(
    const float* __restrict__ X, const float* __restrict__ Wq,
    const float* __restrict__ Wk, const float* __restrict__ Wv,
    float* __restrict__ Qo, float* __restrict__ Ko, float* __restrict__ Vo)
{
    __shared__ float As[16][64];
    __shared__ float Bs[16][64];
    const int m0 = blockIdx.x * 64;
    const int n0 = blockIdx.y * 64;
    const int tid = threadIdx.x;
    const int tx = tid & 15, ty = tid >> 4;
    const int lrow = tid >> 2, lseg = tid & 3;

    const float* Wb; int nb;
    if (n0 < 128)      { Wb = Wq; nb = n0; }
    else if (n0 < 256) { Wb = Wk; nb = n0 - 128; }
    else               { Wb = Wv; nb = n0 - 256; }

    float acc[4][4] = {};
    for (int k0 = 0; k0 < DD; k0 += 16) {
        float4 a  = *(const float4*)(X  + (size_t)(m0 + lrow) * DD + k0 + lseg * 4);
        float4 bv = *(const float4*)(Wb + (size_t)(nb + lrow) * DD + k0 + lseg * 4);
        __syncthreads();
        As[lseg*4+0][lrow] = a.x;  As[lseg*4+1][lrow] = a.y;
        As[lseg*4+2][lrow] = a.z;  As[lseg*4+3][lrow] = a.w;
        Bs[lseg*4+0][lrow] = bv.x; Bs[lseg*4+1][lrow] = bv.y;
        Bs[lseg*4+2][lrow] = bv.z; Bs[lseg*4+3][lrow] = bv.w;
        __syncthreads();
        #pragma unroll
        for (int k = 0; k < 16; ++k) {
            float4 av = *(const float4*)&As[k][ty*4];
            float4 bw = *(const float4*)&Bs[k][tx*4];
            const float* ap = (const float*)&av;
            const float* bp = (const float*)&bw;
            #pragma unroll
            for (int i = 0; i < 4; ++i)
                #pragma unroll
                for (int j = 0; j < 4; ++j)
                    acc[i][j] = fmaf(ap[i], bp[j], acc[i][j]);
        }
    }

    #pragma unroll
    for (int i = 0; i < 4; ++i) {
        const int rg = m0 + ty*4 + i;
        const int bb = rg >> 10, t = rg & 1023;
        #pragma unroll
        for (int j = 0; j < 4; ++j) {
            const int cg = n0 + tx*4 + j;
            const float val = acc[i][j];
            if (cg < 128) {
                const int hh = cg >> 4, f = cg & 15;
                Qo[((size_t)(bb*HH + hh)*TT + t)*FF + f] = val;
            } else if (cg < 256) {
                const int c = cg - 128; const int hh = c >> 4, f = c & 15;
                Ko[((size_t)(bb*HH + hh)*TT + t)*FF + f] = val;
            } else {
                const int c = cg - 256; const int hh = c >> 6, dd = c & 63;
                Vo[((size_t)(bb*HH + hh)*TT + t)*HDIM + dd] = val;
            }
        }
    }
}

// ---------------------------------------------------------------------------
// Kernel 2: split-K causal Taylor attention, ATOMIC-FREE.
// One block = one causal (q-chunk, k-chunk) 128x128 tile pair; 36 pairs x
// 16 (b,h) = 576 equal-work blocks. Block (qt,kc) writes its partial
// num/den with plain coalesced stores into slot kc of NUMp/DENp.
// Slot (kc, qt-region) is written iff kc <= qt == exactly what the
// combiner reads, so no memset and no atomics are needed.
// phi(q).phi(k) == 1 + s + s^2/2,  s = (q.k)/4.
// ---------------------------------------------------------------------------
__global__ __launch_bounds__(256) void attn_chunk_kernel(
    const float* __restrict__ Q, const float* __restrict__ K,
    const float* __restrict__ V, float* __restrict__ NUMp,
    float* __restrict__ DENp)
{
    const int p  = blockIdx.x;   // 0..35
    const int bh = blockIdx.y;   // 0..15

    int qt = (int)((sqrtf(8.0f * p + 1.0f) - 1.0f) * 0.5f);
    while ((qt + 1) * (qt + 2) / 2 <= p) ++qt;
    while (qt * (qt + 1) / 2 > p) --qt;
    const int kc = p - qt * (qt + 1) / 2;

    const int tid = threadIdx.x;
    const int tx = tid & 3;      // col group: cols tx*16 .. tx*16+15
    const int ty = tid >> 2;     // 0..63: q-rows 2ty, 2ty+1

    __shared__ float Ks[128][16];
    __shared__ float Vs[128][64];

    // stage K/V chunk (128 rows)
    {
        const float4* Kb4 = (const float4*)(K + ((size_t)bh*TT + kc*128) * FF);
        float4* Ks4 = (float4*)&Ks[0][0];
        for (int u = tid; u < 512; u += 256) Ks4[u] = Kb4[u];
        const float4* Vb4 = (const float4*)(V + ((size_t)bh*TT + kc*128) * HDIM);
        float4* Vs4 = (float4*)&Vs[0][0];
        for (int u = tid; u < 2048; u += 256) Vs4[u] = Vb4[u];
    }

    // this thread's two q-rows into registers
    float q0[16], q1[16];
    const float* Qb = Q + ((size_t)bh * TT + qt * 128) * FF;
    #pragma unroll
    for (int s = 0; s < 4; ++s) {
        float4 a = *(const float4*)(Qb + (ty*2 + 0)*FF + s*4);
        q0[s*4+0]=a.x; q0[s*4+1]=a.y; q0[s*4+2]=a.z; q0[s*4+3]=a.w;
        float4 b = *(const float4*)(Qb + (ty*2 + 1)*FF + s*4);
        q1[s*4+0]=b.x; q1[s*4+1]=b.y; q1[s*4+2]=b.z; q1[s*4+3]=b.w;
    }
    __syncthreads();

    float num0[16] = {}, num1[16] = {};
    float den0 = 0.f, den1 = 0.f;
    const bool diag = (kc == qt);
    const int r0 = ty * 2, r1 = ty * 2 + 1;

    #pragma unroll 2
    for (int kk = 0; kk < 128; ++kk) {
        float kv[16];
        #pragma unroll
        for (int s = 0; s < 4; ++s) {
            float4 t4 = *(const float4*)&Ks[kk][s*4];
            kv[s*4+0]=t4.x; kv[s*4+1]=t4.y; kv[s*4+2]=t4.z; kv[s*4+3]=t4.w;
        }
        float vv[16];
        #pragma unroll
        for (int s = 0; s < 4; ++s) {
            float4 t4 = *(const float4*)&Vs[kk][tx*16 + s*4];
            vv[s*4+0]=t4.x; vv[s*4+1]=t4.y; vv[s*4+2]=t4.z; vv[s*4+3]=t4.w;
        }
        float s0 = 0.f, s1 = 0.f;
        #pragma unroll
        for (int m = 0; m < 16; ++m) {
            s0 = fmaf(q0[m], kv[m], s0);
            s1 = fmaf(q1[m], kv[m], s1);
        }
        s0 *= 0.25f; s1 *= 0.25f;
        float p0 = fmaf(s0, fmaf(s0, 0.5f, 1.0f), 1.0f);
        float p1 = fmaf(s1, fmaf(s1, 0.5f, 1.0f), 1.0f);
        if (diag) {
            p0 = (kk <= r0) ? p0 : 0.f;
            p1 = (kk <= r1) ? p1 : 0.f;
        }
        den0 += p0; den1 += p1;
        #pragma unroll
        for (int j = 0; j < 16; ++j) {
            num0[j] = fmaf(p0, vv[j], num0[j]);
            num1[j] = fmaf(p1, vv[j], num1[j]);
        }
    }

    // plain-store epilogue into private slot kc
    float* nb = NUMp + (((size_t)kc * (BB*HH) + bh) * TT + qt * 128) * HDIM;
    #pragma unroll
    for (int s = 0; s < 4; ++s) {
        float4 a = { num0[s*4+0], num0[s*4+1], num0[s*4+2], num0[s*4+3] };
        *(float4*)&nb[(size_t)r0 * HDIM + tx*16 + s*4] = a;
        float4 b = { num1[s*4+0], num1[s*4+1], num1[s*4+2], num1[s*4+3] };
        *(float4*)&nb[(size_t)r1 * HDIM + tx*16 + s*4] = b;
    }
    if (tx == 0) {
        float* db = DENp + ((size_t)kc * (BB*HH) + bh) * TT + qt * 128;
        db[r0] = den0;
        db[r1] = den1;
    }
}

// ---------------------------------------------------------------------------
// Kernel 2b: combine slots 0..qt, normalize, relayout to (b, t, h*hd)
// ---------------------------------------------------------------------------
__global__ __launch_bounds__(256) void normalize_kernel(
    const float* __restrict__ NUMp, const float* __restrict__ DENp,
    float* __restrict__ Y)
{
    const int idx = blockIdx.x * 256 + threadIdx.x;  // over 16*1024*16 float4s
    const int c4 = idx & 15;           // 16 float4 per 64-col row
    const int t  = (idx >> 4) & 1023;
    const int bh = idx >> 14;          // 0..15
    const int qt = t >> 7;

    float4 acc = {0.f, 0.f, 0.f, 0.f};
    float den = 0.f;
    for (int kc = 0; kc <= qt; ++kc) {
        const float4* np = (const float4*)(NUMp +
            (((size_t)kc * (BB*HH) + bh) * TT + t) * HDIM);
        float4 v = np[c4];
        acc.x += v.x; acc.y += v.y; acc.z += v.z; acc.w += v.w;
        den += DENp[((size_t)kc * (BB*HH) + bh) * TT + t];
    }
    const float inv = 1.0f / (den + 1e-12f);
    const int b = bh >> 3, h = bh & 7;
    float4 o = { acc.x*inv, acc.y*inv, acc.z*inv, acc.w*inv };
    *(float4*)(Y + ((size_t)(b * TT + t)) * DD + h * HDIM + c4 * 4) = o;
}

// ---------------------------------------------------------------------------
// Kernel 3: output projection.  Out = Y @ Wo^T  (2048 x 512, K=512)
// ---------------------------------------------------------------------------
__global__ __launch_bounds__(256) void out_gemm_kernel(
    const float* __restrict__ Yin, const float* __restrict__ Wo,
    float* __restrict__ Out)
{
    __shared__ float As[16][64];
    __shared__ float Bs[16][64];
    const int m0 = blockIdx.x * 64;
    const int n0 = blockIdx.y * 64;
    const int tid = threadIdx.x;
    const int tx = tid & 15, ty = tid >> 4;
    const int lrow = tid >> 2, lseg = tid & 3;

    float acc[4][4] = {};
    for (int k0 = 0; k0 < DD; k0 += 16) {
        float4 a  = *(const float4*)(Yin + (size_t)(m0 + lrow) * DD + k0 + lseg * 4);
        float4 bv = *(const float4*)(Wo  + (size_t)(n0 + lrow) * DD + k0 + lseg * 4);
        __syncthreads();
        As[lseg*4+0][lrow] = a.x;  As[lseg*4+1][lrow] = a.y;
        As[lseg*4+2][lrow] = a.z;  As[lseg*4+3][lrow] = a.w;
        Bs[lseg*4+0][lrow] = bv.x; Bs[lseg*4+1][lrow] = bv.y;
        Bs[lseg*4+2][lrow] = bv.z; Bs[lseg*4+3][lrow] = bv.w;
        __syncthreads();
        #pragma unroll
        for (int k = 0; k < 16; ++k) {
            float4 av = *(const float4*)&As[k][ty*4];
            float4 bw = *(const float4*)&Bs[k][tx*4];
            const float* ap = (const float*)&av;
            const float* bp = (const float*)&bw;
            #pragma unroll
            for (int i = 0; i < 4; ++i)
                #pragma unroll
                for (int j = 0; j < 4; ++j)
                    acc[i][j] = fmaf(ap[i], bp[j], acc[i][j]);
        }
    }

    #pragma unroll
    for (int i = 0; i < 4; ++i) {
        const int rg = m0 + ty*4 + i;
        #pragma unroll
        for (int j = 0; j < 4; ++j) {
            const int cg = n0 + tx*4 + j;
            Out[(size_t)rg * DD + cg] = acc[i][j];
        }
    }
}

// ---------------------------------------------------------------------------
extern "C" void kernel_launch(void* const* d_in, const int* in_sizes, int n_in,
                              void* d_out, int out_size, void* d_ws, size_t ws_size,
                              hipStream_t stream) {
    const float* X  = (const float*)d_in[0];   // (2,1024,512)
    const float* Wq = (const float*)d_in[1];   // (128,512)
    const float* Wk = (const float*)d_in[2];   // (128,512)
    const float* Wv = (const float*)d_in[3];   // (512,512)
    const float* Wo = (const float*)d_in[4];   // (512,512)
    float* out = (float*)d_out;                // (2,1024,512)

    float* ws = (float*)d_ws;
    float* Qw   = ws;                           // 2*8*1024*16  = 262144 f
    float* Kw   = Qw + (size_t)BB*HH*TT*FF;     // 262144 f
    float* Vw   = Kw + (size_t)BB*HH*TT*FF;     // 1048576 f
    float* Yw   = Vw + (size_t)BB*HH*TT*HDIM;   // 1048576 f
    float* NUMp = Yw + (size_t)BT*DD;           // 8*16*1024*64 = 8388608 f
    float* DENp = NUMp + (size_t)NKC*BB*HH*TT*HDIM; // 131072 f
    // total ~ 11.1M floats = 42.5 MB of d_ws

    dim3 g1(BT/64, 768/64);   // 32 x 12
    qkv_gemm_kernel<<<g1, 256, 0, stream>>>(X, Wq, Wk, Wv, Qw, Kw, Vw);

    dim3 g2(NPAIR, BB*HH);    // 36 x 16 = 576 equal-work blocks
    attn_chunk_kernel<<<g2, 256, 0, stream>>>(Qw, Kw, Vw, NUMp, DENp);

    dim3 g2b((BB*HH*TT*(HDIM/4)) / 256);  // 1024 blocks
    normalize_kernel<<<g2b, 256, 0, stream>>>(NUMp, DENp, Yw);

    dim3 g3(BT/64, DD/64);    // 32 x 8
    out_gemm_kernel<<<g3, 256, 0, stream>>>(Yw, Wo, out);
}

// Round 4
// 72.490 us; speedup vs baseline: 4.7507x; 1.6779x over previous
//
#include <hip/hip_runtime.h>

#define BB 2
#define TT 1024
#define DD 512
#define HH 8
#define FF 16
#define HDIM 64
#define BT (BB*TT)   // 2048

typedef short bf16x8 __attribute__((ext_vector_type(8)));
typedef float f32x4  __attribute__((ext_vector_type(4)));
#define MFMA_BF16 __builtin_amdgcn_mfma_f32_16x16x32_bf16

// float -> bf16 round-to-nearest-even
__device__ __forceinline__ ushort f2b(float f) {
    uint u = __float_as_uint(f);
    uint r = (u + 0x7fffu + ((u >> 16) & 1u)) >> 16;
    return (ushort)r;
}

// ---------------------------------------------------------------------------
// Kernel 0: cast inputs to bf16.  X -> Xb; Wq|Wk|Wv -> Wb[768][512]; Wo -> Wob
// 1664 blocks * 256 thr * 4 elems = 1,703,936 elems exactly.
// ---------------------------------------------------------------------------
__global__ __launch_bounds__(256) void cast_all(
    const float* __restrict__ X,  const float* __restrict__ Wq,
    const float* __restrict__ Wk, const float* __restrict__ Wv,
    const float* __restrict__ Wo,
    ushort* __restrict__ Xb, ushort* __restrict__ Wb, ushort* __restrict__ Wob)
{
    const int i4 = (blockIdx.x * 256 + threadIdx.x) * 4;
    const float* src; ushort* dst;
    if (i4 < 1048576)      { src = X  + i4;             dst = Xb + i4; }
    else if (i4 < 1114112) { src = Wq + (i4 - 1048576); dst = Wb + (i4 - 1048576); }
    else if (i4 < 1179648) { src = Wk + (i4 - 1114112); dst = Wb + 65536 + (i4 - 1114112); }
    else if (i4 < 1441792) { src = Wv + (i4 - 1179648); dst = Wb + 131072 + (i4 - 1179648); }
    else                   { src = Wo + (i4 - 1441792); dst = Wob + (i4 - 1441792); }
    float4 v = *(const float4*)src;
    ushort4 o = { f2b(v.x), f2b(v.y), f2b(v.z), f2b(v.w) };
    *(ushort4*)dst = o;
}

// ---------------------------------------------------------------------------
// Kernel 1: QKV projection, bf16 MFMA, fragments direct from global (L2).
// C[2048 x 768] = Xb @ Wb^T, K=512.  Block tile 64x128, 4 waves (2m x 2n),
// wave tile 32x64.  Epilogue: Q,K -> (bh,t,16) bf16;  V -> Vt[bh][64][1024].
// ---------------------------------------------------------------------------
__global__ __launch_bounds__(256) void qkv_mfma(
    const ushort* __restrict__ Xb, const ushort* __restrict__ Wb,
    ushort* __restrict__ Qb, ushort* __restrict__ Kb, ushort* __restrict__ Vtg)
{
    const int m0 = blockIdx.x * 64, n0 = blockIdx.y * 128;
    const int tid = threadIdx.x, w = tid >> 6, l = tid & 63;
    const int mw = w & 1, nw = w >> 1, lr = l & 15, g = l >> 4;

    f32x4 acc[2][4] = {};
    const ushort* Ar = Xb + (size_t)(m0 + mw*32 + lr) * 512 + g*8;
    const ushort* Br = Wb + (size_t)(n0 + nw*64 + lr) * 512 + g*8;

    #pragma unroll 4
    for (int ks = 0; ks < 16; ++ks) {
        bf16x8 a0 = *(const bf16x8*)(Ar + ks*32);
        bf16x8 a1 = *(const bf16x8*)(Ar + (size_t)16*512 + ks*32);
        bf16x8 b0 = *(const bf16x8*)(Br + ks*32);
        bf16x8 b1 = *(const bf16x8*)(Br + (size_t)16*512 + ks*32);
        bf16x8 b2 = *(const bf16x8*)(Br + (size_t)32*512 + ks*32);
        bf16x8 b3 = *(const bf16x8*)(Br + (size_t)48*512 + ks*32);
        acc[0][0] = MFMA_BF16(a0, b0, acc[0][0], 0, 0, 0);
        acc[0][1] = MFMA_BF16(a0, b1, acc[0][1], 0, 0, 0);
        acc[0][2] = MFMA_BF16(a0, b2, acc[0][2], 0, 0, 0);
        acc[0][3] = MFMA_BF16(a0, b3, acc[0][3], 0, 0, 0);
        acc[1][0] = MFMA_BF16(a1, b0, acc[1][0], 0, 0, 0);
        acc[1][1] = MFMA_BF16(a1, b1, acc[1][1], 0, 0, 0);
        acc[1][2] = MFMA_BF16(a1, b2, acc[1][2], 0, 0, 0);
        acc[1][3] = MFMA_BF16(a1, b3, acc[1][3], 0, 0, 0);
    }

    if (n0 < 256) {
        // Q (n0==0) or K (n0==128): feat n in 0..127 -> h=n>>4, f=n&15
        ushort* Dst = (n0 == 0) ? Qb : Kb;
        #pragma unroll
        for (int mb = 0; mb < 2; ++mb)
            #pragma unroll
            for (int nb = 0; nb < 4; ++nb) {
                const int n = nw*64 + nb*16 + lr;
                const int h = n >> 4, f = n & 15;
                #pragma unroll
                for (int r = 0; r < 4; ++r) {
                    const int tok = m0 + mw*32 + mb*16 + g*4 + r;
                    const int b = tok >> 10, tt = tok & 1023;
                    Dst[(((size_t)(b*HH + h)) * TT + tt) * FF + f] = f2b(acc[mb][nb][r]);
                }
            }
    } else {
        // V: feat n-256 in 0..511 -> h=(n-256)>>6, v=(n-256)&63; transposed store
        #pragma unroll
        for (int mb = 0; mb < 2; ++mb)
            #pragma unroll
            for (int nb = 0; nb < 4; ++nb) {
                const int n = n0 + nw*64 + nb*16 + lr - 256;
                const int h = n >> 6, v = n & 63;
                const int tok0 = m0 + mw*32 + mb*16 + g*4;
                const int b = tok0 >> 10, tt = tok0 & 1023;
                uint lo = (uint)f2b(acc[mb][nb][0]) | ((uint)f2b(acc[mb][nb][1]) << 16);
                uint hi = (uint)f2b(acc[mb][nb][2]) | ((uint)f2b(acc[mb][nb][3]) << 16);
                uint2 pk = { lo, hi };
                *(uint2*)&Vtg[(((size_t)(b*HH + h)) * 64 + v) * TT + tt] = pk;
            }
    }
}

// ---------------------------------------------------------------------------
// Kernel 2: causal Taylor attention, bf16 MFMA, fully wave-local.
// phi(q).phi(k) = 1 + s + s^2/2, s = (q.k)/4.
// Grid (16 qpair, 16 bh) x 256 thr. Wave w: qsel=w>>1 picks q-tile
// {qp, 31-qp} (balanced total kc work), vh=w&1 picks v-half (redundant QK^T).
// Per kc (64 keys): S^T = mfma(K,Q) (f=16 via zeroed hi-frags); poly+mask+den
// in VALU on C-regs; pack bf16 -> LDS P[q32][k64]; PV: O^T += mfma(Vt, P).
// No block barriers anywhere (wave-local LDS regions, in-order DS per wave).
// ---------------------------------------------------------------------------
__global__ __launch_bounds__(256) void attn_mfma(
    const ushort* __restrict__ Qb, const ushort* __restrict__ Kb,
    const ushort* __restrict__ Vtg, ushort* __restrict__ Yb)
{
    __shared__ short Vt[2][64][72];   // [qsel][v][k64+8pad]
    __shared__ short Pl[4][32][72];   // [wave][q32][k64+8pad]

    const int qp = blockIdx.x, bh = blockIdx.y;
    const int b = bh >> 3, h = bh & 7;
    const int tid = threadIdx.x, w = tid >> 6, l = tid & 63;
    const int qsel = w >> 1, vh = w & 1, lr = l & 15, g = l >> 4;
    const int qt = qsel ? (31 - qp) : qp;
    const int nkc = (qt >> 1) + 1;
    const bf16x8 zf = {0,0,0,0,0,0,0,0};

    // hoist Q B-fragments (f=16: lanes g>=2 hold zeros)
    bf16x8 qf[2];
    #pragma unroll
    for (int nb = 0; nb < 2; ++nb)
        qf[nb] = (l < 32)
            ? *(const bf16x8*)(Qb + ((size_t)bh*TT + qt*32 + nb*16 + lr)*FF + g*8)
            : zf;

    f32x4 o[2][2] = {};     // o[mv][nb]: O^T fragments
    float den[2] = {0.f, 0.f};

    for (int kc = 0; kc < nkc; ++kc) {
        // stage this wave's v-half of Vt (coalesced from pre-transposed Vtg)
        {
            const int r = vh*32 + (l >> 1);
            const int half = (l & 1) * 32;
            const ushort* src = Vtg + ((size_t)bh*64 + r)*TT + kc*64 + half;
            short* dstp = &Vt[qsel][r][half];
            *(bf16x8*)(dstp)      = *(const bf16x8*)(src);
            *(bf16x8*)(dstp + 8)  = *(const bf16x8*)(src + 8);
            *(bf16x8*)(dstp + 16) = *(const bf16x8*)(src + 16);
            *(bf16x8*)(dstp + 24) = *(const bf16x8*)(src + 24);
        }

        // S^T = K . Q^T  (swapped), poly+mask+den, pack -> P LDS
        #pragma unroll
        for (int mb = 0; mb < 4; ++mb) {
            bf16x8 kf = (l < 32)
                ? *(const bf16x8*)(Kb + ((size_t)bh*TT + kc*64 + mb*16 + lr)*FF + g*8)
                : zf;
            #pragma unroll
            for (int nb = 0; nb < 2; ++nb) {
                f32x4 z4 = {};
                f32x4 s = MFMA_BF16(kf, qf[nb], z4, 0, 0, 0);
                const int qg = qt*32 + nb*16 + lr;
                const int kg0 = kc*64 + mb*16 + g*4;
                float pv[4];
                #pragma unroll
                for (int r = 0; r < 4; ++r) {
                    float ss = s[r] * 0.25f;
                    float pp = fmaf(ss, fmaf(ss, 0.5f, 1.0f), 1.0f);
                    if (kg0 + r > qg) pp = 0.f;
                    den[nb] += pp;
                    pv[r] = pp;
                }
                uint2 pk = { (uint)f2b(pv[0]) | ((uint)f2b(pv[1]) << 16),
                             (uint)f2b(pv[2]) | ((uint)f2b(pv[3]) << 16) };
                *(uint2*)&Pl[w][nb*16 + lr][mb*16 + g*4] = pk;
            }
        }

        // O^T += V^T . P   (A = Vt rows, B = P rows, both 16B LDS reads)
        #pragma unroll
        for (int kb = 0; kb < 2; ++kb)
            #pragma unroll
            for (int mv = 0; mv < 2; ++mv) {
                bf16x8 vf = *(const bf16x8*)&Vt[qsel][vh*32 + mv*16 + lr][kb*32 + g*8];
                #pragma unroll
                for (int nb = 0; nb < 2; ++nb) {
                    bf16x8 pf = *(const bf16x8*)&Pl[w][nb*16 + lr][kb*32 + g*8];
                    o[mv][nb] = MFMA_BF16(vf, pf, o[mv][nb], 0, 0, 0);
                }
            }
    }

    // epilogue: den reduce across lane groups, normalize, store bf16 Y
    #pragma unroll
    for (int nb = 0; nb < 2; ++nb) {
        float d = den[nb];
        d += __shfl_xor(d, 16);
        d += __shfl_xor(d, 32);
        const float inv = 1.0f / (d + 1e-12f);
        const int t = qt*32 + nb*16 + lr;
        #pragma unroll
        for (int mv = 0; mv < 2; ++mv) {
            f32x4 ov = o[mv][nb];
            uint2 pk = { (uint)f2b(ov[0]*inv) | ((uint)f2b(ov[1]*inv) << 16),
                         (uint)f2b(ov[2]*inv) | ((uint)f2b(ov[3]*inv) << 16) };
            *(uint2*)(Yb + ((size_t)(b*TT + t))*DD + h*HDIM + vh*32 + mv*16 + g*4) = pk;
        }
    }
}

// ---------------------------------------------------------------------------
// Kernel 3: output projection, bf16 MFMA.  Out[2048 x 512] = Yb @ Wob^T, f32 out
// ---------------------------------------------------------------------------
__global__ __launch_bounds__(256) void out_mfma(
    const ushort* __restrict__ Yb, const ushort* __restrict__ Wob,
    float* __restrict__ Out)
{
    const int m0 = blockIdx.x * 64, n0 = blockIdx.y * 64;
    const int tid = threadIdx.x, w = tid >> 6, l = tid & 63;
    const int mw = w & 1, nw = w >> 1, lr = l & 15, g = l >> 4;

    f32x4 acc[2][2] = {};
    const ushort* Ar = Yb  + (size_t)(m0 + mw*32 + lr) * 512 + g*8;
    const ushort* Br = Wob + (size_t)(n0 + nw*32 + lr) * 512 + g*8;

    #pragma unroll 4
    for (int ks = 0; ks < 16; ++ks) {
        bf16x8 a0 = *(const bf16x8*)(Ar + ks*32);
        bf16x8 a1 = *(const bf16x8*)(Ar + (size_t)16*512 + ks*32);
        bf16x8 b0 = *(const bf16x8*)(Br + ks*32);
        bf16x8 b1 = *(const bf16x8*)(Br + (size_t)16*512 + ks*32);
        acc[0][0] = MFMA_BF16(a0, b0, acc[0][0], 0, 0, 0);
        acc[0][1] = MFMA_BF16(a0, b1, acc[0][1], 0, 0, 0);
        acc[1][0] = MFMA_BF16(a1, b0, acc[1][0], 0, 0, 0);
        acc[1][1] = MFMA_BF16(a1, b1, acc[1][1], 0, 0, 0);
    }

    #pragma unroll
    for (int mb = 0; mb < 2; ++mb)
        #pragma unroll
        for (int nb = 0; nb < 2; ++nb) {
            const int n = n0 + nw*32 + nb*16 + lr;
            const int m = m0 + mw*32 + mb*16 + g*4;
            #pragma unroll
            for (int r = 0; r < 4; ++r)
                Out[(size_t)(m + r)*512 + n] = acc[mb][nb][r];
        }
}

// ---------------------------------------------------------------------------
extern "C" void kernel_launch(void* const* d_in, const int* in_sizes, int n_in,
                              void* d_out, int out_size, void* d_ws, size_t ws_size,
                              hipStream_t stream) {
    const float* X  = (const float*)d_in[0];   // (2,1024,512)
    const float* Wq = (const float*)d_in[1];   // (128,512)
    const float* Wk = (const float*)d_in[2];   // (128,512)
    const float* Wv = (const float*)d_in[3];   // (512,512)
    const float* Wo = (const float*)d_in[4];   // (512,512)
    float* out = (float*)d_out;                // (2,1024,512)

    ushort* ws = (ushort*)d_ws;
    ushort* Xb  = ws;                    // 2048*512   = 1048576
    ushort* Wb  = Xb  + 1048576;         // 768*512    = 393216
    ushort* Wob = Wb  + 393216;          // 512*512    = 262144
    ushort* Qb  = Wob + 262144;          // 16*1024*16 = 262144
    ushort* Kb  = Qb  + 262144;          // 262144
    ushort* Vtg = Kb  + 262144;          // 16*64*1024 = 1048576
    ushort* Yb  = Vtg + 1048576;         // 2048*512   = 1048576
    // total 4,325,376 ushorts = 8.65 MB

    cast_all<<<1664, 256, 0, stream>>>(X, Wq, Wk, Wv, Wo, Xb, Wb, Wob);

    dim3 g1(BT/64, 768/128);  // 32 x 6
    qkv_mfma<<<g1, 256, 0, stream>>>(Xb, Wb, Qb, Kb, Vtg);

    dim3 g2(16, BB*HH);       // 16 qpairs x 16 bh = 256 blocks
    attn_mfma<<<g2, 256, 0, stream>>>(Qb, Kb, Vtg, Yb);

    dim3 g3(BT/64, DD/64);    // 32 x 8
    out_mfma<<<g3, 256, 0, stream>>>(Yb, Wob, out);
}